// Round 3
// baseline (794.912 us; speedup 1.0000x reference)
//
#include <hip/hip_runtime.h>
#include <hip/hip_fp16.h>
#include <hip/hip_bf16.h>

constexpr int BB  = 8;
constexpr int NN  = 4096;
constexpr int CC  = 256;
constexpr int CKK = 32;

typedef __attribute__((ext_vector_type(8))) short    short8;  // 8 x bf16 bits
typedef __attribute__((ext_vector_type(8))) _Float16 half8;
typedef __attribute__((ext_vector_type(4))) _Float16 half4;
typedef __attribute__((ext_vector_type(4))) float    f32x4;

__device__ __forceinline__ unsigned short bf16_bits(float v) {
    __hip_bfloat16 h = __float2bfloat16(v);
    return *reinterpret_cast<unsigned short*>(&h);
}
__device__ __forceinline__ float bf16_val(unsigned short u) {
    __hip_bfloat16 h = *reinterpret_cast<__hip_bfloat16*>(&u);
    return __bfloat162float(h);
}

// ---------------------------------------------------------------------------
// K0: transpose + bf16 hi/lo split of all weights into WT[576][256]:
// rows 0..255 = Wh cols, 256..287 = Wf, 288..319 = Wg, 320..575 = Wo.
// B-frag layout needs W^T[n][k], k-major per lane.
// ---------------------------------------------------------------------------
__global__ __launch_bounds__(256) void prep_kernel(
    const float* __restrict__ Wf, const float* __restrict__ Wg,
    const float* __restrict__ Wh, const float* __restrict__ Wo,
    unsigned short* __restrict__ WThi, unsigned short* __restrict__ WTlo)
{
    const int n = blockIdx.x;      // output column (0..575)
    const int k = threadIdx.x;     // input channel (0..255)
    float v;
    if      (n < 256) v = Wh[k * 256 + n];
    else if (n < 288) v = Wf[k * 32 + (n - 256)];
    else if (n < 320) v = Wg[k * 32 + (n - 288)];
    else              v = Wo[k * 256 + (n - 320)];
    const unsigned short hi = bf16_bits(v);
    WThi[n * 256 + k] = hi;
    WTlo[n * 256 + k] = bf16_bits(v - bf16_val(hi));
}

// ---------------------------------------------------------------------------
// K1: fused projections as one MFMA GEMM [32768 x 256] @ [256 x 320].
// Block = 64 pixels, 4 waves x 16 pixels, each wave does all 20 N-tiles.
// A (x fp32) split to bf16 hi/lo on the fly; 3-term split MFMA.
// Epilogue: hh -> fp16 TRANSPOSED hhT[b][c][n] (packed 8B stores, natural
// from C-layout: rows are consecutive n); f,g -> fp16 [n][d].
// ---------------------------------------------------------------------------
__global__ __launch_bounds__(256) void fgh_kernel(
    const float* __restrict__ x,
    const unsigned short* __restrict__ WThi, const unsigned short* __restrict__ WTlo,
    const float* __restrict__ bf, const float* __restrict__ bg,
    const float* __restrict__ bh,
    _Float16* __restrict__ fbuf, _Float16* __restrict__ gbuf,
    _Float16* __restrict__ hhT)
{
    const int tid = threadIdx.x, w = tid >> 6, lane = tid & 63;
    const int ln = lane & 15, lq = lane >> 4;
    const int px0 = blockIdx.x * 64 + w * 16;   // global pixel base (b*NN+n)

    f32x4 acc[20];
    #pragma unroll
    for (int i = 0; i < 20; ++i) acc[i] = {0.f, 0.f, 0.f, 0.f};

    #pragma unroll 1
    for (int kc = 0; kc < 8; ++kc) {
        const int k0 = kc * 32;
        float av[8];
        const float* xp = &x[(size_t)(px0 + ln) * CC + k0 + lq * 8];
        *(float4*)&av[0] = *(const float4*)xp;
        *(float4*)&av[4] = *(const float4*)(xp + 4);
        short8 Ahi, Alo;
        #pragma unroll
        for (int j = 0; j < 8; ++j) {
            const unsigned short h = bf16_bits(av[j]);
            Ahi[j] = (short)h;
            Alo[j] = (short)bf16_bits(av[j] - bf16_val(h));
        }
        #pragma unroll
        for (int nt = 0; nt < 20; ++nt) {
            const size_t boff = (size_t)(nt * 16 + ln) * 256 + k0 + lq * 8;
            const short8 Bhi = *(const short8*)&WThi[boff];
            const short8 Blo = *(const short8*)&WTlo[boff];
            acc[nt] = __builtin_amdgcn_mfma_f32_16x16x32_bf16(Ahi, Bhi, acc[nt], 0, 0, 0);
            acc[nt] = __builtin_amdgcn_mfma_f32_16x16x32_bf16(Ahi, Blo, acc[nt], 0, 0, 0);
            acc[nt] = __builtin_amdgcn_mfma_f32_16x16x32_bf16(Alo, Bhi, acc[nt], 0, 0, 0);
        }
    }

    const int b = px0 >> 12, nb = px0 & (NN - 1);
    // hh: tiles 0..15, transposed fp16 write (4 consecutive n per lane)
    #pragma unroll
    for (int nt = 0; nt < 16; ++nt) {
        const int c = nt * 16 + ln;
        const float bias = bh[c];
        half4 hv;
        #pragma unroll
        for (int r = 0; r < 4; ++r) hv[r] = (_Float16)(acc[nt][r] + bias);
        *(half4*)&hhT[((size_t)(b * CC + c)) * NN + nb + lq * 4] = hv;
    }
    // f: tiles 16,17 ; g: tiles 18,19  (fp16 [n][d])
    #pragma unroll
    for (int hf = 0; hf < 2; ++hf) {
        const int d = hf * 16 + ln;
        const float biasf = bf[d], biasg = bg[d];
        #pragma unroll
        for (int r = 0; r < 4; ++r) {
            const size_t row = (size_t)(px0 + lq * 4 + r) * CKK + d;
            fbuf[row] = (_Float16)(acc[16 + hf][r] + biasf);
            gbuf[row] = (_Float16)(acc[18 + hf][r] + biasg);
        }
    }
}

// ---------------------------------------------------------------------------
// K2: MFMA flash attention, register-only inner loop (NO LDS in k-loop).
// Block = 32 queries of batch b; 4 waves = 2 c-halves x 2 key-halves.
// S^T = f x g per 16key x 16q tile (single f16 K32 MFMA): C-layout puts
// q on lanes, keys on regs == EXACTLY the 16x16x16f16 A-frag layout, so
// exp'd P feeds PV directly from registers. Partial O/rowsum merged in LDS.
// ---------------------------------------------------------------------------
__global__ __launch_bounds__(256) void attn_kernel(
    const _Float16* __restrict__ fbuf, const _Float16* __restrict__ gbuf,
    const _Float16* __restrict__ hhT, float* __restrict__ obuf)
{
    __shared__ float Obuf[32 * 256];   // kh=1 partial O
    __shared__ float rsbuf[64];        // rowsums per key-half
    __shared__ float mxbuf[64];        // rowmax per key-half

    const int tid = threadIdx.x, w = tid >> 6, lane = tid & 63;
    const int ln = lane & 15, lq = lane >> 4;
    const int ch = w & 1, kh = w >> 1;
    const int b  = blockIdx.x & 7;     // batch == XCD (hhT[b] L2-pinned)
    const int q0 = (blockIdx.x >> 3) * 32;

    // persistent g B-frags (q on lanes, d k-major)
    half8 Bg[2];
    #pragma unroll
    for (int qt = 0; qt < 2; ++qt)
        Bg[qt] = *(const half8*)&gbuf[(size_t)(b * NN + q0 + qt * 16 + ln) * CKK + lq * 8];

    const f32x4 zero = {0.f, 0.f, 0.f, 0.f};
    const int jbeg = kh * 2048, jend = jbeg + 2048;

    // ---- pass 1: rowmax over this wave's key-half ----
    float mx2[2] = {-1e30f, -1e30f};
    #pragma unroll 1
    for (int j0 = jbeg; j0 < jend; j0 += 64) {
        #pragma unroll
        for (int kt = 0; kt < 4; ++kt) {
            const half8 Af = *(const half8*)
                &fbuf[(size_t)(b * NN + j0 + kt * 16 + ln) * CKK + lq * 8];
            #pragma unroll
            for (int qt = 0; qt < 2; ++qt) {
                const f32x4 s = __builtin_amdgcn_mfma_f32_16x16x32_f16(Af, Bg[qt], zero, 0, 0, 0);
                mx2[qt] = fmaxf(mx2[qt], fmaxf(fmaxf(s[0], s[1]), fmaxf(s[2], s[3])));
            }
        }
    }
    #pragma unroll
    for (int qt = 0; qt < 2; ++qt) {
        mx2[qt] = fmaxf(mx2[qt], __shfl_xor(mx2[qt], 16));
        mx2[qt] = fmaxf(mx2[qt], __shfl_xor(mx2[qt], 32));
    }
    if (ch == 0 && lane < 16) {
        mxbuf[kh * 32 + ln]      = mx2[0];
        mxbuf[kh * 32 + 16 + ln] = mx2[1];
    }
    __syncthreads();

    constexpr float LOG2E = 1.4426950408889634f;
    float mk[2];
    #pragma unroll
    for (int qt = 0; qt < 2; ++qt)
        mk[qt] = fmaxf(mxbuf[qt * 16 + ln], mxbuf[32 + qt * 16 + ln]) * LOG2E;

    // ---- pass 2: S -> exp -> (register) P -> PV, rowsum per-lane scalar ----
    f32x4 O[2][8];
    #pragma unroll
    for (int qt = 0; qt < 2; ++qt)
        #pragma unroll
        for (int ct = 0; ct < 8; ++ct) O[qt][ct] = zero;
    float rs_s[2] = {0.f, 0.f};

    #pragma unroll 1
    for (int j0 = jbeg; j0 < jend; j0 += 64) {
        #pragma unroll
        for (int kt = 0; kt < 4; ++kt) {
            const half8 Af = *(const half8*)
                &fbuf[(size_t)(b * NN + j0 + kt * 16 + ln) * CKK + lq * 8];
            half4 Bh[8];
            #pragma unroll
            for (int ct = 0; ct < 8; ++ct)
                Bh[ct] = *(const half4*)
                    &hhT[((size_t)(b * CC + ch * 128 + ct * 16 + ln)) * NN + j0 + kt * 16 + lq * 4];
            #pragma unroll
            for (int qt = 0; qt < 2; ++qt) {
                const f32x4 s = __builtin_amdgcn_mfma_f32_16x16x32_f16(Af, Bg[qt], zero, 0, 0, 0);
                half4 Ap;
                float psum = 0.f;
                #pragma unroll
                for (int r = 0; r < 4; ++r) {
                    const float p = exp2f(fmaf(s[r], LOG2E, -mk[qt]));
                    psum += p;
                    Ap[r] = (_Float16)p;
                }
                rs_s[qt] += psum;
                #pragma unroll
                for (int ct = 0; ct < 8; ++ct)
                    O[qt][ct] = __builtin_amdgcn_mfma_f32_16x16x16f16(Ap, Bh[ct], O[qt][ct], 0, 0, 0);
            }
        }
    }

    // ---- merge key-halves ----
    #pragma unroll
    for (int qt = 0; qt < 2; ++qt) {
        rs_s[qt] += __shfl_xor(rs_s[qt], 16);
        rs_s[qt] += __shfl_xor(rs_s[qt], 32);
    }
    if (ch == 0 && lane < 16) {
        rsbuf[kh * 32 + ln]      = rs_s[0];
        rsbuf[kh * 32 + 16 + ln] = rs_s[1];
    }
    if (kh == 1) {
        #pragma unroll
        for (int qt = 0; qt < 2; ++qt)
            #pragma unroll
            for (int ct = 0; ct < 8; ++ct)
                #pragma unroll
                for (int r = 0; r < 4; ++r)
                    Obuf[(qt * 16 + lq * 4 + r) * 256 + ch * 128 + ct * 16 + ln] = O[qt][ct][r];
    }
    __syncthreads();
    if (kh == 0) {
        #pragma unroll
        for (int qt = 0; qt < 2; ++qt)
            #pragma unroll
            for (int r = 0; r < 4; ++r) {
                const int q = qt * 16 + lq * 4 + r;
                const float rinv = 1.0f / (rsbuf[q] + rsbuf[32 + q]);
                #pragma unroll
                for (int ct = 0; ct < 8; ++ct) {
                    const int c = ch * 128 + ct * 16 + ln;
                    obuf[((size_t)(b * NN + q0 + q)) * CC + c] =
                        (O[qt][ct][r] + Obuf[q * 256 + c]) * rinv;
                }
            }
    }
}

// ---------------------------------------------------------------------------
// K3: out = gamma * (o @ Wo + bo) + x   (MFMA, o split on the fly)
// ---------------------------------------------------------------------------
__global__ __launch_bounds__(256) void out_kernel(
    const float* __restrict__ obuf,
    const unsigned short* __restrict__ WThi, const unsigned short* __restrict__ WTlo,
    const float* __restrict__ bo, const float* __restrict__ gamma,
    const float* __restrict__ x, float* __restrict__ out)
{
    const int tid = threadIdx.x, w = tid >> 6, lane = tid & 63;
    const int ln = lane & 15, lq = lane >> 4;
    const int px0 = blockIdx.x * 64 + w * 16;

    f32x4 acc[16];
    #pragma unroll
    for (int i = 0; i < 16; ++i) acc[i] = {0.f, 0.f, 0.f, 0.f};

    #pragma unroll 1
    for (int kc = 0; kc < 8; ++kc) {
        const int k0 = kc * 32;
        float av[8];
        const float* op = &obuf[(size_t)(px0 + ln) * CC + k0 + lq * 8];
        *(float4*)&av[0] = *(const float4*)op;
        *(float4*)&av[4] = *(const float4*)(op + 4);
        short8 Ahi, Alo;
        #pragma unroll
        for (int j = 0; j < 8; ++j) {
            const unsigned short h = bf16_bits(av[j]);
            Ahi[j] = (short)h;
            Alo[j] = (short)bf16_bits(av[j] - bf16_val(h));
        }
        #pragma unroll
        for (int nt = 0; nt < 16; ++nt) {
            const size_t boff = (size_t)(320 + nt * 16 + ln) * 256 + k0 + lq * 8;
            const short8 Bhi = *(const short8*)&WThi[boff];
            const short8 Blo = *(const short8*)&WTlo[boff];
            acc[nt] = __builtin_amdgcn_mfma_f32_16x16x32_bf16(Ahi, Bhi, acc[nt], 0, 0, 0);
            acc[nt] = __builtin_amdgcn_mfma_f32_16x16x32_bf16(Ahi, Blo, acc[nt], 0, 0, 0);
            acc[nt] = __builtin_amdgcn_mfma_f32_16x16x32_bf16(Alo, Bhi, acc[nt], 0, 0, 0);
        }
    }

    const float gm = gamma[0];
    #pragma unroll
    for (int nt = 0; nt < 16; ++nt) {
        const int c = nt * 16 + ln;
        const float bias = bo[c];
        #pragma unroll
        for (int r = 0; r < 4; ++r) {
            const size_t idx = (size_t)(px0 + lq * 4 + r) * CC + c;
            out[idx] = gm * (acc[nt][r] + bias) + x[idx];
        }
    }
}

// ---------------------------------------------------------------------------
extern "C" void kernel_launch(void* const* d_in, const int* in_sizes, int n_in,
                              void* d_out, int out_size, void* d_ws, size_t ws_size,
                              hipStream_t stream)
{
    (void)in_sizes; (void)n_in; (void)out_size; (void)ws_size;

    const float* x     = (const float*)d_in[0];
    const float* Wf    = (const float*)d_in[1];
    const float* bf    = (const float*)d_in[2];
    const float* Wg    = (const float*)d_in[3];
    const float* bg    = (const float*)d_in[4];
    const float* Wh    = (const float*)d_in[5];
    const float* bh    = (const float*)d_in[6];
    const float* Wo    = (const float*)d_in[7];
    const float* bo    = (const float*)d_in[8];
    const float* gamma = (const float*)d_in[9];
    float* out = (float*)d_out;

    // ws: f(2MB) | g(2MB) | hhT(16MB) | o(32MB) | WThi | WTlo (~0.6MB)
    _Float16* fbuf = (_Float16*)d_ws;
    _Float16* gbuf = fbuf + (size_t)BB * NN * CKK;
    _Float16* hhT  = gbuf + (size_t)BB * NN * CKK;
    float*    obuf = (float*)(hhT + (size_t)BB * CC * NN);
    unsigned short* WThi = (unsigned short*)(obuf + (size_t)BB * NN * CC);
    unsigned short* WTlo = WThi + (size_t)576 * 256;

    prep_kernel<<<576, 256, 0, stream>>>(Wf, Wg, Wh, Wo, WThi, WTlo);
    fgh_kernel<<<BB * NN / 64, 256, 0, stream>>>(x, WThi, WTlo, bf, bg, bh,
                                                 fbuf, gbuf, hhT);
    attn_kernel<<<BB * NN / 32, 256, 0, stream>>>(fbuf, gbuf, hhT, obuf);
    out_kernel<<<BB * NN / 64, 256, 0, stream>>>(obuf, WThi, WTlo, bo, gamma, x, out);
}

// Round 4
// 576.494 us; speedup vs baseline: 1.3789x; 1.3789x over previous
//
#include <hip/hip_runtime.h>
#include <hip/hip_fp16.h>
#include <hip/hip_bf16.h>

constexpr int BB  = 8;
constexpr int NN  = 4096;
constexpr int CC  = 256;
constexpr int CKK = 32;

typedef __attribute__((ext_vector_type(8))) short    short8;  // 8 x bf16 bits
typedef __attribute__((ext_vector_type(8))) _Float16 half8;
typedef __attribute__((ext_vector_type(4))) _Float16 half4;
typedef __attribute__((ext_vector_type(4))) float    f32x4;

#define GPTR(x) ((const __attribute__((address_space(1))) void*)(x))
#define LPTR(x) ((__attribute__((address_space(3))) void*)(x))

__device__ __forceinline__ unsigned short bf16_bits(float v) {
    __hip_bfloat16 h = __float2bfloat16(v);
    return *reinterpret_cast<unsigned short*>(&h);
}
__device__ __forceinline__ float bf16_val(unsigned short u) {
    __hip_bfloat16 h = *reinterpret_cast<__hip_bfloat16*>(&u);
    return __bfloat162float(h);
}

// ---------------------------------------------------------------------------
// K0: transpose + bf16 hi/lo split of all weights into WT[576][256]:
// rows 0..255 = Wh cols, 256..287 = Wf, 288..319 = Wg, 320..575 = Wo.
// ---------------------------------------------------------------------------
__global__ __launch_bounds__(256) void prep_kernel(
    const float* __restrict__ Wf, const float* __restrict__ Wg,
    const float* __restrict__ Wh, const float* __restrict__ Wo,
    unsigned short* __restrict__ WThi, unsigned short* __restrict__ WTlo)
{
    const int n = blockIdx.x;
    const int k = threadIdx.x;
    float v;
    if      (n < 256) v = Wh[k * 256 + n];
    else if (n < 288) v = Wf[k * 32 + (n - 256)];
    else if (n < 320) v = Wg[k * 32 + (n - 288)];
    else              v = Wo[k * 256 + (n - 320)];
    const unsigned short hi = bf16_bits(v);
    WThi[n * 256 + k] = hi;
    WTlo[n * 256 + k] = bf16_bits(v - bf16_val(hi));
}

// ---------------------------------------------------------------------------
// K1: fused projections as one MFMA GEMM [32768 x 256] @ [256 x 320].
// hhT written fp16 transposed [b][c][n] with 8-key segments XOR-swizzled by
// (c&7) inside each 64-key group, so the attn kernel's LDS B-frag reads are
// bank-conflict-free after a verbatim global->LDS DMA copy.
// ---------------------------------------------------------------------------
__global__ __launch_bounds__(256) void fgh_kernel(
    const float* __restrict__ x,
    const unsigned short* __restrict__ WThi, const unsigned short* __restrict__ WTlo,
    const float* __restrict__ bf, const float* __restrict__ bg,
    const float* __restrict__ bh,
    _Float16* __restrict__ fbuf, _Float16* __restrict__ gbuf,
    _Float16* __restrict__ hhT)
{
    const int tid = threadIdx.x, w = tid >> 6, lane = tid & 63;
    const int ln = lane & 15, lq = lane >> 4;
    const int px0 = blockIdx.x * 64 + w * 16;   // global pixel base (b*NN+n)

    f32x4 acc[20];
    #pragma unroll
    for (int i = 0; i < 20; ++i) acc[i] = {0.f, 0.f, 0.f, 0.f};

    #pragma unroll 1
    for (int kc = 0; kc < 8; ++kc) {
        const int k0 = kc * 32;
        float av[8];
        const float* xp = &x[(size_t)(px0 + ln) * CC + k0 + lq * 8];
        *(float4*)&av[0] = *(const float4*)xp;
        *(float4*)&av[4] = *(const float4*)(xp + 4);
        short8 Ahi, Alo;
        #pragma unroll
        for (int j = 0; j < 8; ++j) {
            const unsigned short h = bf16_bits(av[j]);
            Ahi[j] = (short)h;
            Alo[j] = (short)bf16_bits(av[j] - bf16_val(h));
        }
        #pragma unroll
        for (int nt = 0; nt < 20; ++nt) {
            const size_t boff = (size_t)(nt * 16 + ln) * 256 + k0 + lq * 8;
            const short8 Bhi = *(const short8*)&WThi[boff];
            const short8 Blo = *(const short8*)&WTlo[boff];
            acc[nt] = __builtin_amdgcn_mfma_f32_16x16x32_bf16(Ahi, Bhi, acc[nt], 0, 0, 0);
            acc[nt] = __builtin_amdgcn_mfma_f32_16x16x32_bf16(Ahi, Blo, acc[nt], 0, 0, 0);
            acc[nt] = __builtin_amdgcn_mfma_f32_16x16x32_bf16(Alo, Bhi, acc[nt], 0, 0, 0);
        }
    }

    const int b = px0 >> 12, nb = px0 & (NN - 1);
    // hh: tiles 0..15, transposed fp16 write with key-segment swizzle
    #pragma unroll
    for (int nt = 0; nt < 16; ++nt) {
        const int c = nt * 16 + ln;
        const float bias = bh[c];
        half4 hv;
        #pragma unroll
        for (int r = 0; r < 4; ++r) hv[r] = (_Float16)(acc[nt][r] + bias);
        const int n   = nb + lq * 4;                       // 4 pixels, same seg
        const int nsw = (n & ~63) | (((((n & 63) >> 3) ^ (c & 7)) << 3) | (n & 7));
        *(half4*)&hhT[((size_t)(b * CC + c)) * NN + nsw] = hv;
    }
    // f: tiles 16,17 ; g: tiles 18,19  (fp16 [n][d], natural layout)
    #pragma unroll
    for (int hf = 0; hf < 2; ++hf) {
        const int d = hf * 16 + ln;
        const float biasf = bf[d], biasg = bg[d];
        #pragma unroll
        for (int r = 0; r < 4; ++r) {
            const size_t row = (size_t)(px0 + lq * 4 + r) * CKK + d;
            fbuf[row] = (_Float16)(acc[16 + hf][r] + biasf);
            gbuf[row] = (_Float16)(acc[18 + hf][r] + biasg);
        }
    }
}

// ---------------------------------------------------------------------------
// K2: MFMA flash attention, barrier-free k-loop.
// Block = 64 queries x 256 c of one batch; 4 waves each own 64 channels and
// recompute S (dup, but sync-free). hh tiles DMA-staged (global_load_lds,
// double-buffered, wave-private rows). S^T C-layout feeds K16 PV A-frags
// straight from registers. One __syncthreads total (after pass-1 rowmax).
// ---------------------------------------------------------------------------
__global__ __launch_bounds__(256) void attn_kernel(
    const _Float16* __restrict__ fbuf, const _Float16* __restrict__ gbuf,
    const _Float16* __restrict__ hhT, float* __restrict__ obuf)
{
    __shared__ _Float16 Ht[2][256 * 64];   // [buf][c][64 keys, seg-swizzled]
    __shared__ float mxbuf[4][64];
    __shared__ float rsbuf[64];

    const int tid = threadIdx.x, w = tid >> 6, lane = tid & 63;
    const int ln = lane & 15, lq = lane >> 4;
    const int b  = blockIdx.x & 7;               // batch == XCD
    const int q0 = (blockIdx.x >> 3) * 64;
    const int cb = w * 64;                       // this wave's channel base

    const f32x4 zero = {0.f, 0.f, 0.f, 0.f};
    constexpr float LOG2E = 1.4426950408889634f;

    // per-lane source/dest for the 1KB DMA chunks (rows cb+i*8, 8 lanes/row)
    const _Float16* gsrc0 = hhT + ((size_t)(b * CC + cb + (lane >> 3)) * NN) + (lane & 7) * 8;

    // ---- prologue: stage tile j0=0 into buf 0 (latency hidden by pass 1) ----
    #pragma unroll
    for (int i = 0; i < 8; ++i)
        __builtin_amdgcn_global_load_lds(GPTR(gsrc0 + (size_t)i * 8 * NN),
                                         LPTR(&Ht[0][(cb + i * 8) * 64]), 16, 0, 0);

    // persistent g B-frags: B[k=d][n=q], 4 q-tiles
    half8 Bg[4];
    #pragma unroll
    for (int qt = 0; qt < 4; ++qt)
        Bg[qt] = *(const half8*)&gbuf[(size_t)(b * NN + q0 + qt * 16 + ln) * CKK + lq * 8];

    // ---- pass 1: rowmax (keys split across waves; merged once) ----
    float mx[4];
    #pragma unroll
    for (int qt = 0; qt < 4; ++qt) mx[qt] = -1e30f;
    #pragma unroll 1
    for (int j0 = 0; j0 < NN; j0 += 64) {
        const half8 Af = *(const half8*)
            &fbuf[(size_t)(b * NN + j0 + w * 16 + ln) * CKK + lq * 8];
        #pragma unroll
        for (int qt = 0; qt < 4; ++qt) {
            const f32x4 s = __builtin_amdgcn_mfma_f32_16x16x32_f16(Af, Bg[qt], zero, 0, 0, 0);
            mx[qt] = fmaxf(mx[qt], fmaxf(fmaxf(s[0], s[1]), fmaxf(s[2], s[3])));
        }
    }
    #pragma unroll
    for (int qt = 0; qt < 4; ++qt) {
        mx[qt] = fmaxf(mx[qt], __shfl_xor(mx[qt], 16));
        mx[qt] = fmaxf(mx[qt], __shfl_xor(mx[qt], 32));
    }
    if (lane < 16) {
        #pragma unroll
        for (int qt = 0; qt < 4; ++qt) mxbuf[w][qt * 16 + ln] = mx[qt];
    }
    __syncthreads();   // the only block-wide barrier
    float mk[4];
    #pragma unroll
    for (int qt = 0; qt < 4; ++qt)
        mk[qt] = LOG2E * fmaxf(fmaxf(mxbuf[0][qt * 16 + ln], mxbuf[1][qt * 16 + ln]),
                               fmaxf(mxbuf[2][qt * 16 + ln], mxbuf[3][qt * 16 + ln]));

    // ---- pass 2: S -> exp -> (register) P -> PV from LDS-staged hh ----
    f32x4 O[4][4];     // [qt][ct]
    #pragma unroll
    for (int qt = 0; qt < 4; ++qt)
        #pragma unroll
        for (int ct = 0; ct < 4; ++ct) O[qt][ct] = zero;
    float ps[4] = {0.f, 0.f, 0.f, 0.f};

    #pragma unroll 1
    for (int j0 = 0; j0 < NN; j0 += 64) {
        const int buf = (j0 >> 6) & 1;

        // S phase: all 64 keys, exp'd P held in registers (K16 A-frag layout)
        half4 Ap[4][4];   // [kt][qt]
        #pragma unroll
        for (int kt = 0; kt < 4; ++kt) {
            const half8 Af = *(const half8*)
                &fbuf[(size_t)(b * NN + j0 + kt * 16 + ln) * CKK + lq * 8];
            #pragma unroll
            for (int qt = 0; qt < 4; ++qt) {
                const f32x4 s = __builtin_amdgcn_mfma_f32_16x16x32_f16(Af, Bg[qt], zero, 0, 0, 0);
                float psum = 0.f;
                #pragma unroll
                for (int r = 0; r < 4; ++r) {
                    const float p = exp2f(fmaf(s[r], LOG2E, -mk[qt]));
                    psum += p;
                    Ap[kt][qt][r] = (_Float16)p;
                }
                ps[qt] += psum;
            }
        }

        // PV phase: B-frags from swizzled LDS tile (conflict-free b64 reads)
        #pragma unroll
        for (int kt = 0; kt < 4; ++kt) {
            #pragma unroll
            for (int ct = 0; ct < 4; ++ct) {
                const int c = cb + ct * 16 + ln;
                const int phys = (2 * kt + (lq >> 1)) ^ (ln & 7);
                const half4 Bh = *(const half4*)&Ht[buf][c * 64 + phys * 8 + 4 * (lq & 1)];
                #pragma unroll
                for (int qt = 0; qt < 4; ++qt)
                    O[qt][ct] = __builtin_amdgcn_mfma_f32_16x16x16f16(Ap[kt][qt], Bh, O[qt][ct], 0, 0, 0);
            }
        }

        // prefetch next tile into the other buffer (covered by next S phase)
        if (j0 + 64 < NN) {
            const _Float16* gs = gsrc0 + j0 + 64;
            #pragma unroll
            for (int i = 0; i < 8; ++i)
                __builtin_amdgcn_global_load_lds(GPTR(gs + (size_t)i * 8 * NN),
                                                 LPTR(&Ht[buf ^ 1][(cb + i * 8) * 64]), 16, 0, 0);
        }
    }

    // ---- rowsum merge (within-wave; all waves produce identical values) ----
    #pragma unroll
    for (int qt = 0; qt < 4; ++qt) {
        ps[qt] += __shfl_xor(ps[qt], 16);
        ps[qt] += __shfl_xor(ps[qt], 32);
    }
    if (lane < 16) {
        #pragma unroll
        for (int qt = 0; qt < 4; ++qt) rsbuf[qt * 16 + ln] = ps[qt];
    }

    // ---- epilogue: normalize, store ----
    #pragma unroll
    for (int qt = 0; qt < 4; ++qt)
        #pragma unroll
        for (int r = 0; r < 4; ++r) {
            const int q = qt * 16 + lq * 4 + r;
            const float rinv = 1.0f / rsbuf[q];
            #pragma unroll
            for (int ct = 0; ct < 4; ++ct)
                obuf[((size_t)(b * NN + q0 + q)) * CC + cb + ct * 16 + ln] = O[qt][ct][r] * rinv;
        }
}

// ---------------------------------------------------------------------------
// K3: out = gamma * (o @ Wo + bo) + x   (MFMA, o split on the fly)
// ---------------------------------------------------------------------------
__global__ __launch_bounds__(256) void out_kernel(
    const float* __restrict__ obuf,
    const unsigned short* __restrict__ WThi, const unsigned short* __restrict__ WTlo,
    const float* __restrict__ bo, const float* __restrict__ gamma,
    const float* __restrict__ x, float* __restrict__ out)
{
    const int tid = threadIdx.x, w = tid >> 6, lane = tid & 63;
    const int ln = lane & 15, lq = lane >> 4;
    const int px0 = blockIdx.x * 64 + w * 16;

    f32x4 acc[16];
    #pragma unroll
    for (int i = 0; i < 16; ++i) acc[i] = {0.f, 0.f, 0.f, 0.f};

    #pragma unroll 1
    for (int kc = 0; kc < 8; ++kc) {
        const int k0 = kc * 32;
        float av[8];
        const float* op = &obuf[(size_t)(px0 + ln) * CC + k0 + lq * 8];
        *(float4*)&av[0] = *(const float4*)op;
        *(float4*)&av[4] = *(const float4*)(op + 4);
        short8 Ahi, Alo;
        #pragma unroll
        for (int j = 0; j < 8; ++j) {
            const unsigned short h = bf16_bits(av[j]);
            Ahi[j] = (short)h;
            Alo[j] = (short)bf16_bits(av[j] - bf16_val(h));
        }
        #pragma unroll
        for (int nt = 0; nt < 16; ++nt) {
            const size_t boff = (size_t)(320 + nt * 16 + ln) * 256 + k0 + lq * 8;
            const short8 Bhi = *(const short8*)&WThi[boff];
            const short8 Blo = *(const short8*)&WTlo[boff];
            acc[nt] = __builtin_amdgcn_mfma_f32_16x16x32_bf16(Ahi, Bhi, acc[nt], 0, 0, 0);
            acc[nt] = __builtin_amdgcn_mfma_f32_16x16x32_bf16(Ahi, Blo, acc[nt], 0, 0, 0);
            acc[nt] = __builtin_amdgcn_mfma_f32_16x16x32_bf16(Alo, Bhi, acc[nt], 0, 0, 0);
        }
    }

    const float gm = gamma[0];
    #pragma unroll
    for (int nt = 0; nt < 16; ++nt) {
        const int c = nt * 16 + ln;
        const float bias = bo[c];
        #pragma unroll
        for (int r = 0; r < 4; ++r) {
            const size_t idx = (size_t)(px0 + lq * 4 + r) * CC + c;
            out[idx] = gm * (acc[nt][r] + bias) + x[idx];
        }
    }
}

// ---------------------------------------------------------------------------
extern "C" void kernel_launch(void* const* d_in, const int* in_sizes, int n_in,
                              void* d_out, int out_size, void* d_ws, size_t ws_size,
                              hipStream_t stream)
{
    (void)in_sizes; (void)n_in; (void)out_size; (void)ws_size;

    const float* x     = (const float*)d_in[0];
    const float* Wf    = (const float*)d_in[1];
    const float* bf    = (const float*)d_in[2];
    const float* Wg    = (const float*)d_in[3];
    const float* bg    = (const float*)d_in[4];
    const float* Wh    = (const float*)d_in[5];
    const float* bh    = (const float*)d_in[6];
    const float* Wo    = (const float*)d_in[7];
    const float* bo    = (const float*)d_in[8];
    const float* gamma = (const float*)d_in[9];
    float* out = (float*)d_out;

    // ws: f(2MB) | g(2MB) | hhT(16MB) | o(32MB) | WThi | WTlo (~0.6MB)
    _Float16* fbuf = (_Float16*)d_ws;
    _Float16* gbuf = fbuf + (size_t)BB * NN * CKK;
    _Float16* hhT  = gbuf + (size_t)BB * NN * CKK;
    float*    obuf = (float*)(hhT + (size_t)BB * CC * NN);
    unsigned short* WThi = (unsigned short*)(obuf + (size_t)BB * NN * CC);
    unsigned short* WTlo = WThi + (size_t)576 * 256;

    prep_kernel<<<576, 256, 0, stream>>>(Wf, Wg, Wh, Wo, WThi, WTlo);
    fgh_kernel<<<BB * NN / 64, 256, 0, stream>>>(x, WThi, WTlo, bf, bg, bh,
                                                 fbuf, gbuf, hhT);
    attn_kernel<<<BB * NN / 64, 256, 0, stream>>>(fbuf, gbuf, hhT, obuf);
    out_kernel<<<BB * NN / 64, 256, 0, stream>>>(obuf, WThi, WTlo, bo, gamma, x, out);
}

// Round 5
// 332.243 us; speedup vs baseline: 2.3926x; 1.7352x over previous
//
#include <hip/hip_runtime.h>
#include <hip/hip_fp16.h>
#include <hip/hip_bf16.h>

constexpr int BB  = 8;
constexpr int NN  = 4096;
constexpr int CC  = 256;
constexpr int CKK = 32;

typedef __attribute__((ext_vector_type(8))) short    short8;  // 8 x bf16 bits
typedef __attribute__((ext_vector_type(8))) _Float16 half8;
typedef __attribute__((ext_vector_type(4))) _Float16 half4;
typedef __attribute__((ext_vector_type(4))) float    f32x4;

__device__ __forceinline__ unsigned short bf16_bits(float v) {
    __hip_bfloat16 h = __float2bfloat16(v);
    return *reinterpret_cast<unsigned short*>(&h);
}
__device__ __forceinline__ float bf16_val(unsigned short u) {
    __hip_bfloat16 h = *reinterpret_cast<__hip_bfloat16*>(&u);
    return __bfloat162float(h);
}

// ---------------------------------------------------------------------------
// K0: transpose + bf16 hi/lo split of all weights into WT[576][256]:
// rows 0..255 = Wh cols, 256..287 = Wf, 288..319 = Wg, 320..575 = Wo.
// ---------------------------------------------------------------------------
__global__ __launch_bounds__(256) void prep_kernel(
    const float* __restrict__ Wf, const float* __restrict__ Wg,
    const float* __restrict__ Wh, const float* __restrict__ Wo,
    unsigned short* __restrict__ WThi, unsigned short* __restrict__ WTlo)
{
    const int n = blockIdx.x;
    const int k = threadIdx.x;
    float v;
    if      (n < 256) v = Wh[k * 256 + n];
    else if (n < 288) v = Wf[k * 32 + (n - 256)];
    else if (n < 320) v = Wg[k * 32 + (n - 288)];
    else              v = Wo[k * 256 + (n - 320)];
    const unsigned short hi = bf16_bits(v);
    WThi[n * 256 + k] = hi;
    WTlo[n * 256 + k] = bf16_bits(v - bf16_val(hi));
}

// ---------------------------------------------------------------------------
// K1: projections as tiled GEMM [32768 x 256] @ [256 x 320].
// Block = 256 M x 64 N (grid 128 x 5); wave = 64M x 64N = 16 acc tiles.
// 48 MFMA per 32-k step vs 8 B-loads -> MFMA-bound.
// nb 0..3: hh channels -> fp16 transposed hhT[b][c][n] (plain layout).
// nb 4: f (nt 0,1) and g (nt 2,3) -> fp16 [n][d].
// ---------------------------------------------------------------------------
__global__ __launch_bounds__(256) void fgh_kernel(
    const float* __restrict__ x,
    const unsigned short* __restrict__ WThi, const unsigned short* __restrict__ WTlo,
    const float* __restrict__ bf, const float* __restrict__ bg,
    const float* __restrict__ bh,
    _Float16* __restrict__ fbuf, _Float16* __restrict__ gbuf,
    _Float16* __restrict__ hhT)
{
    const int tid = threadIdx.x, w = tid >> 6, lane = tid & 63;
    const int ln = lane & 15, lq = lane >> 4;
    const int px0 = blockIdx.x * 256 + w * 64;   // this wave's first pixel
    const int n0  = blockIdx.y * 64;             // output-column base (0..256)

    f32x4 acc[4][4];   // [mt][nt]
    #pragma unroll
    for (int i = 0; i < 4; ++i)
        #pragma unroll
        for (int j = 0; j < 4; ++j) acc[i][j] = {0.f, 0.f, 0.f, 0.f};

    #pragma unroll 1
    for (int kc = 0; kc < 8; ++kc) {
        const int k0 = kc * 32;
        short8 Ahi[4], Alo[4];
        #pragma unroll
        for (int mt = 0; mt < 4; ++mt) {
            float av[8];
            const float* xp = &x[(size_t)(px0 + mt * 16 + ln) * CC + k0 + lq * 8];
            *(float4*)&av[0] = *(const float4*)xp;
            *(float4*)&av[4] = *(const float4*)(xp + 4);
            #pragma unroll
            for (int j = 0; j < 8; ++j) {
                const unsigned short h = bf16_bits(av[j]);
                Ahi[mt][j] = (short)h;
                Alo[mt][j] = (short)bf16_bits(av[j] - bf16_val(h));
            }
        }
        #pragma unroll
        for (int nt = 0; nt < 4; ++nt) {
            const size_t boff = (size_t)(n0 + nt * 16 + ln) * 256 + k0 + lq * 8;
            const short8 Bhi = *(const short8*)&WThi[boff];
            const short8 Blo = *(const short8*)&WTlo[boff];
            #pragma unroll
            for (int mt = 0; mt < 4; ++mt) {
                acc[mt][nt] = __builtin_amdgcn_mfma_f32_16x16x32_bf16(Ahi[mt], Bhi, acc[mt][nt], 0, 0, 0);
                acc[mt][nt] = __builtin_amdgcn_mfma_f32_16x16x32_bf16(Ahi[mt], Blo, acc[mt][nt], 0, 0, 0);
                acc[mt][nt] = __builtin_amdgcn_mfma_f32_16x16x32_bf16(Alo[mt], Bhi, acc[mt][nt], 0, 0, 0);
            }
        }
    }

    const int b = px0 >> 12;
    if (blockIdx.y < 4) {
        // hh channels n0..n0+63 -> transposed fp16 store
        #pragma unroll
        for (int nt = 0; nt < 4; ++nt) {
            const int c = n0 + nt * 16 + ln;
            const float bias = bh[c];
            #pragma unroll
            for (int mt = 0; mt < 4; ++mt) {
                half4 hv;
                #pragma unroll
                for (int r = 0; r < 4; ++r) hv[r] = (_Float16)(acc[mt][nt][r] + bias);
                const int npix = (px0 & (NN - 1)) + mt * 16 + lq * 4;
                *(half4*)&hhT[((size_t)(b * CC + c)) * NN + npix] = hv;
            }
        }
    } else {
        // f (nt 0,1), g (nt 2,3): d = (nt&1)*16 + ln
        #pragma unroll
        for (int nt = 0; nt < 4; ++nt) {
            const int d = (nt & 1) * 16 + ln;
            const float bias = (nt < 2) ? bf[d] : bg[d];
            _Float16* dst = (nt < 2) ? fbuf : gbuf;
            #pragma unroll
            for (int mt = 0; mt < 4; ++mt)
                #pragma unroll
                for (int r = 0; r < 4; ++r)
                    dst[(size_t)(px0 + mt * 16 + lq * 4 + r) * CKK + d] =
                        (_Float16)(acc[mt][nt][r] + bias);
        }
    }
}

// ---------------------------------------------------------------------------
// K2: MFMA flash attention, shared-P structure, all-K32.
// Block = 64 q x 256 c of one batch; 4 waves. Per 64-key iter:
//   phase A: wave w computes S^T for ITS 16 keys x 64 q (4 MFMA, no dup),
//            exp -> fp16 P -> shared LDS tile (A-layout, pad-72, dbuf)
//   barrier (1/iter)
//   phase B: wave w PVs its 64 channels: A=P (LDS), B=hhT (global b128,
//            issued pre-barrier so the barrier vmcnt-drain covers latency)
// Rowmax pass-1 identical-instruction trick keeps exp <= 1 (fp16-safe).
// ---------------------------------------------------------------------------
__global__ __launch_bounds__(256) void attn_kernel(
    const _Float16* __restrict__ fbuf, const _Float16* __restrict__ gbuf,
    const _Float16* __restrict__ hhT, float* __restrict__ obuf)
{
    __shared__ _Float16 P[2][64 * 72];   // 18 KB, dbuf
    __shared__ float mxbuf[4][64];
    __shared__ float rsbuf[4][64];

    const int tid = threadIdx.x, w = tid >> 6, lane = tid & 63;
    const int ln = lane & 15, lq = lane >> 4;
    const int b  = blockIdx.x & 7;               // batch == XCD
    const int q0 = (blockIdx.x >> 3) * 64;
    const int cb = w * 64;                       // this wave's channel base

    const f32x4 zero = {0.f, 0.f, 0.f, 0.f};
    constexpr float LOG2E = 1.4426950408889634f;

    // persistent g B-frags: B[k=d][n=q]
    half8 Bg[4];
    #pragma unroll
    for (int qt = 0; qt < 4; ++qt)
        Bg[qt] = *(const half8*)&gbuf[(size_t)(b * NN + q0 + qt * 16 + ln) * CKK + lq * 8];

    // ---- pass 1: rowmax (wave w covers keys j0 + w*16 + 0..15) ----
    float mx[4];
    #pragma unroll
    for (int qt = 0; qt < 4; ++qt) mx[qt] = -1e30f;
    #pragma unroll 1
    for (int j0 = 0; j0 < NN; j0 += 64) {
        const half8 Af = *(const half8*)
            &fbuf[(size_t)(b * NN + j0 + w * 16 + ln) * CKK + lq * 8];
        #pragma unroll
        for (int qt = 0; qt < 4; ++qt) {
            const f32x4 s = __builtin_amdgcn_mfma_f32_16x16x32_f16(Af, Bg[qt], zero, 0, 0, 0);
            mx[qt] = fmaxf(mx[qt], fmaxf(fmaxf(s[0], s[1]), fmaxf(s[2], s[3])));
        }
    }
    #pragma unroll
    for (int qt = 0; qt < 4; ++qt) {
        mx[qt] = fmaxf(mx[qt], __shfl_xor(mx[qt], 16));
        mx[qt] = fmaxf(mx[qt], __shfl_xor(mx[qt], 32));
    }
    if (lane < 16) {
        #pragma unroll
        for (int qt = 0; qt < 4; ++qt) mxbuf[w][qt * 16 + ln] = mx[qt];
    }
    __syncthreads();
    float mk[4];   // per-lane: q = qt*16 + ln
    #pragma unroll
    for (int qt = 0; qt < 4; ++qt)
        mk[qt] = LOG2E * fmaxf(fmaxf(mxbuf[0][qt * 16 + ln], mxbuf[1][qt * 16 + ln]),
                               fmaxf(mxbuf[2][qt * 16 + ln], mxbuf[3][qt * 16 + ln]));

    // ---- main loop ----
    f32x4 O[4][4];     // [qt][ct]
    #pragma unroll
    for (int qt = 0; qt < 4; ++qt)
        #pragma unroll
        for (int ct = 0; ct < 4; ++ct) O[qt][ct] = zero;
    float psum[4] = {0.f, 0.f, 0.f, 0.f};

    #pragma unroll 1
    for (int j0 = 0; j0 < NN; j0 += 64) {
        const int buf = (j0 >> 6) & 1;

        // PV B-frags for THIS iter: global b128, issued before the barrier
        half8 Bh[4][2];
        #pragma unroll
        for (int ct = 0; ct < 4; ++ct)
            #pragma unroll
            for (int kh = 0; kh < 2; ++kh)
                Bh[ct][kh] = *(const half8*)
                    &hhT[((size_t)(b * CC + cb + ct * 16 + ln)) * NN + j0 + kh * 32 + lq * 8];

        // phase A: S^T for this wave's 16 keys x 64 q
        const half8 Af = *(const half8*)
            &fbuf[(size_t)(b * NN + j0 + w * 16 + ln) * CKK + lq * 8];
        #pragma unroll
        for (int qt = 0; qt < 4; ++qt) {
            const f32x4 s = __builtin_amdgcn_mfma_f32_16x16x32_f16(Af, Bg[qt], zero, 0, 0, 0);
            half4 ph;
            float ps = 0.f;
            #pragma unroll
            for (int r = 0; r < 4; ++r) {
                const float p = exp2f(fmaf(s[r], LOG2E, -mk[qt]));
                ps += p;
                ph[r] = (_Float16)p;
            }
            psum[qt] += ps;
            // P[q = qt*16+ln][key = w*16 + lq*4 + r]  (A-layout, pad 72)
            *(half4*)&P[buf][(qt * 16 + ln) * 72 + w * 16 + lq * 4] = ph;
        }
        __syncthreads();

        // phase B: PV for this wave's 64 channels, K=64 via 2 K32 halves
        #pragma unroll
        for (int qt = 0; qt < 4; ++qt) {
            const half8 Ap0 = *(const half8*)&P[buf][(qt * 16 + ln) * 72 + lq * 8];
            const half8 Ap1 = *(const half8*)&P[buf][(qt * 16 + ln) * 72 + 32 + lq * 8];
            #pragma unroll
            for (int ct = 0; ct < 4; ++ct) {
                O[qt][ct] = __builtin_amdgcn_mfma_f32_16x16x32_f16(Ap0, Bh[ct][0], O[qt][ct], 0, 0, 0);
                O[qt][ct] = __builtin_amdgcn_mfma_f32_16x16x32_f16(Ap1, Bh[ct][1], O[qt][ct], 0, 0, 0);
            }
        }
    }

    // ---- rowsum merge across waves ----
    #pragma unroll
    for (int qt = 0; qt < 4; ++qt) {
        psum[qt] += __shfl_xor(psum[qt], 16);
        psum[qt] += __shfl_xor(psum[qt], 32);
    }
    if (lane < 16) {
        #pragma unroll
        for (int qt = 0; qt < 4; ++qt) rsbuf[w][qt * 16 + ln] = psum[qt];
    }
    __syncthreads();

    // ---- epilogue: normalize, store (row-indexed q) ----
    #pragma unroll
    for (int qt = 0; qt < 4; ++qt)
        #pragma unroll
        for (int r = 0; r < 4; ++r) {
            const int q = qt * 16 + lq * 4 + r;
            const float rinv = 1.0f / (rsbuf[0][q] + rsbuf[1][q] + rsbuf[2][q] + rsbuf[3][q]);
            #pragma unroll
            for (int ct = 0; ct < 4; ++ct)
                obuf[((size_t)(b * NN + q0 + q)) * CC + cb + ct * 16 + ln] = O[qt][ct][r] * rinv;
        }
}

// ---------------------------------------------------------------------------
// K3: out = gamma * (o @ Wo + bo) + x  as tiled GEMM [32768x256]@[256x256].
// Same structure as fgh_kernel, grid 128 x 4.
// ---------------------------------------------------------------------------
__global__ __launch_bounds__(256) void out_kernel(
    const float* __restrict__ obuf,
    const unsigned short* __restrict__ WThi, const unsigned short* __restrict__ WTlo,
    const float* __restrict__ bo, const float* __restrict__ gamma,
    const float* __restrict__ x, float* __restrict__ out)
{
    const int tid = threadIdx.x, w = tid >> 6, lane = tid & 63;
    const int ln = lane & 15, lq = lane >> 4;
    const int px0 = blockIdx.x * 256 + w * 64;
    const int n0  = blockIdx.y * 64;

    f32x4 acc[4][4];
    #pragma unroll
    for (int i = 0; i < 4; ++i)
        #pragma unroll
        for (int j = 0; j < 4; ++j) acc[i][j] = {0.f, 0.f, 0.f, 0.f};

    #pragma unroll 1
    for (int kc = 0; kc < 8; ++kc) {
        const int k0 = kc * 32;
        short8 Ahi[4], Alo[4];
        #pragma unroll
        for (int mt = 0; mt < 4; ++mt) {
            float av[8];
            const float* op = &obuf[(size_t)(px0 + mt * 16 + ln) * CC + k0 + lq * 8];
            *(float4*)&av[0] = *(const float4*)op;
            *(float4*)&av[4] = *(const float4*)(op + 4);
            #pragma unroll
            for (int j = 0; j < 8; ++j) {
                const unsigned short h = bf16_bits(av[j]);
                Ahi[mt][j] = (short)h;
                Alo[mt][j] = (short)bf16_bits(av[j] - bf16_val(h));
            }
        }
        #pragma unroll
        for (int nt = 0; nt < 4; ++nt) {
            const size_t boff = (size_t)(320 + n0 + nt * 16 + ln) * 256 + k0 + lq * 8;
            const short8 Bhi = *(const short8*)&WThi[boff];
            const short8 Blo = *(const short8*)&WTlo[boff];
            #pragma unroll
            for (int mt = 0; mt < 4; ++mt) {
                acc[mt][nt] = __builtin_amdgcn_mfma_f32_16x16x32_bf16(Ahi[mt], Bhi, acc[mt][nt], 0, 0, 0);
                acc[mt][nt] = __builtin_amdgcn_mfma_f32_16x16x32_bf16(Ahi[mt], Blo, acc[mt][nt], 0, 0, 0);
                acc[mt][nt] = __builtin_amdgcn_mfma_f32_16x16x32_bf16(Alo[mt], Bhi, acc[mt][nt], 0, 0, 0);
            }
        }
    }

    const float gm = gamma[0];
    #pragma unroll
    for (int nt = 0; nt < 4; ++nt) {
        const int c = n0 + nt * 16 + ln;
        const float bias = bo[c];
        #pragma unroll
        for (int mt = 0; mt < 4; ++mt)
            #pragma unroll
            for (int r = 0; r < 4; ++r) {
                const size_t idx = (size_t)(px0 + mt * 16 + lq * 4 + r) * CC + c;
                out[idx] = gm * (acc[mt][nt][r] + bias) + x[idx];
            }
    }
}

// ---------------------------------------------------------------------------
extern "C" void kernel_launch(void* const* d_in, const int* in_sizes, int n_in,
                              void* d_out, int out_size, void* d_ws, size_t ws_size,
                              hipStream_t stream)
{
    (void)in_sizes; (void)n_in; (void)out_size; (void)ws_size;

    const float* x     = (const float*)d_in[0];
    const float* Wf    = (const float*)d_in[1];
    const float* bf    = (const float*)d_in[2];
    const float* Wg    = (const float*)d_in[3];
    const float* bg    = (const float*)d_in[4];
    const float* Wh    = (const float*)d_in[5];
    const float* bh    = (const float*)d_in[6];
    const float* Wo    = (const float*)d_in[7];
    const float* bo    = (const float*)d_in[8];
    const float* gamma = (const float*)d_in[9];
    float* out = (float*)d_out;

    // ws: f(2MB) | g(2MB) | hhT(16MB) | o(32MB) | WThi | WTlo (~0.6MB)
    _Float16* fbuf = (_Float16*)d_ws;
    _Float16* gbuf = fbuf + (size_t)BB * NN * CKK;
    _Float16* hhT  = gbuf + (size_t)BB * NN * CKK;
    float*    obuf = (float*)(hhT + (size_t)BB * CC * NN);
    unsigned short* WThi = (unsigned short*)(obuf + (size_t)BB * NN * CC);
    unsigned short* WTlo = WThi + (size_t)576 * 256;

    prep_kernel<<<576, 256, 0, stream>>>(Wf, Wg, Wh, Wo, WThi, WTlo);
    fgh_kernel<<<dim3(BB * NN / 256, 5), 256, 0, stream>>>(x, WThi, WTlo, bf, bg, bh,
                                                           fbuf, gbuf, hhT);
    attn_kernel<<<BB * NN / 64, 256, 0, stream>>>(fbuf, gbuf, hhT, obuf);
    out_kernel<<<dim3(BB * NN / 256, 4), 256, 0, stream>>>(obuf, WThi, WTlo, bo, gamma, x, out);
}